// Round 3
// baseline (175.473 us; speedup 1.0000x reference)
//
#include <hip/hip_runtime.h>

#define NUM 16
#define TPB 256
#define TILES 4
#define TRACKS_PER_TILE (TPB / 4)                   // 64 tracks per tile per block
#define TRACKS_PER_BLOCK (TRACKS_PER_TILE * TILES)  // 256 tracks per block

// Round-8 (resubmit after container infra failure): 4-lane cooperative rows
// (zero LDS, zero barriers) + REAL memory-level parallelism:
//  - TILES=4: 24 loads (~6 KB payload) per wave issued before any compute
//  - __launch_bounds__(256,4): VGPR budget 128 so the payload can stay live
//    (round-7's (256,8) made the compiler squeeze to 24 VGPR and serialize
//    the tiles -> MLP collapsed -> 2.4 TB/s latency plateau)
//  - sched_barrier(0) after the load block: compiler may not sink loads
//    below compute.
// Concurrency target: ~20 waves/CU x 6 KB = ~120 KB in flight per CU vs the
// ~22 KB needed to sustain 6.3 TB/s at ~900 cy latency.
__global__ __launch_bounds__(TPB, 4) void kf_update_kernel(
    const float* __restrict__ value,   // (B, 32)
    const float* __restrict__ vel,     // (B, 32)
    const float* __restrict__ Pin,     // (B, 16, 4, 4)
    const float* __restrict__ obs,     // (B, 32)
    const int*   __restrict__ lm,      // (B, 16)
    const int*   __restrict__ mask,    // (B, 16)
    float* __restrict__ out,           // rv(B*32) | rm(B*16) | rvel(B*32) | rP(B*256)
    int Bn)
{
    const int tid = threadIdx.x;
    const int r   = tid & 3;    // row of the 4x4 this lane owns
    const int sub = tid >> 2;   // track slot within block (0..63)
    const int total = Bn * NUM;

    float* __restrict__ rv_out   = out;
    float* __restrict__ rm_out   = out + (size_t)Bn * 32;
    float* __restrict__ rvel_out = out + (size_t)Bn * 48;
    float* __restrict__ rP_out   = out + (size_t)Bn * 80;

    const int base = blockIdx.x * TRACKS_PER_BLOCK + sub;

    int    t[TILES];
    bool   act[TILES];
    float4 Pr[TILES];
    float2 v2[TILES], u2[TILES], o2[TILES];
    int    lv[TILES], mv[TILES];

    // ---- issue ALL loads for all 4 tiles before any compute ----
    #pragma unroll
    for (int k = 0; k < TILES; ++k) {
        t[k]   = base + k * TRACKS_PER_TILE;
        act[k] = t[k] < total;
        const int tc = act[k] ? t[k] : 0;
        // P row r of track tc: float4 index 4*tc + r == wave-contiguous
        Pr[k] = reinterpret_cast<const float4*>(Pin)[(size_t)tc * 4 + r];
        v2[k] = reinterpret_cast<const float2*>(value)[tc];
        u2[k] = reinterpret_cast<const float2*>(vel)[tc];
        o2[k] = reinterpret_cast<const float2*>(obs)[tc];
        lv[k] = lm[tc];
        mv[k] = mask[tc];
    }
    // Do not let the scheduler sink any of the loads below this point.
    __builtin_amdgcn_sched_barrier(0);

    // ---- compute + store per tile ----
    #pragma unroll
    for (int k = 0; k < TILES; ++k) {
        // pred = F @ [vx,vy,ux,uy]; lane owns component r
        const float pr = (r == 0) ? (v2[k].x + u2[k].x)
                       : (r == 1) ? (v2[k].y + u2[k].y)
                       : (r == 2) ? u2[k].x
                                  : u2[k].y;

        // Q = F @ P : rows 0,1 add rows 2,3 (quad shuffle xor 2)
        float q0 = Pr[k].x, q1 = Pr[k].y, q2 = Pr[k].z, q3 = Pr[k].w;
        const float x0 = __shfl_xor(q0, 2);
        const float x1 = __shfl_xor(q1, 2);
        const float x2 = __shfl_xor(q2, 2);
        const float x3 = __shfl_xor(q3, 2);
        if (r < 2) { q0 += x0; q1 += x1; q2 += x2; q3 += x3; }

        // pP = Q @ F^T : per-row column adds (intra-lane)
        const float a0 = q0 + q2;
        const float a1 = q1 + q3;
        const float a2 = q2;
        const float a3 = q3;

        // broadcast pP rows 0 and 1 to the quad
        const float r00 = __shfl(a0, 0, 4), r01 = __shfl(a1, 0, 4);
        const float r02 = __shfl(a2, 0, 4), r03 = __shfl(a3, 0, 4);
        const float r10 = __shfl(a0, 1, 4), r11 = __shfl(a1, 1, 4);
        const float r12 = __shfl(a2, 1, 4), r13 = __shfl(a3, 1, 4);

        // S = pP[:2,:2] + 1e-5 I ; closed-form inverse folded into K
        const float S00 = r00 + 1e-5f;
        const float S01 = r01;
        const float S10 = r10;
        const float S11 = r11 + 1e-5f;
        const float rdet = 1.0f / (S00 * S11 - S01 * S10);

        // K row r
        const float K0 = (a0 * S11 - a1 * S10) * rdet;
        const float K1 = (a1 * S00 - a0 * S01) * rdet;

        // innovation needs pred rows 0,1
        const float p0 = __shfl(pr, 0, 4);
        const float p1 = __shfl(pr, 1, 4);
        const float y0 = o2[k].x - p0;
        const float y1 = o2[k].y - p1;
        const float updr = pr + K0 * y0 + K1 * y1;

        // Pn row r = pP_r - (K0 * pP_row0 + K1 * pP_row1)
        const float Pn0 = a0 - (K0 * r00 + K1 * r10);
        const float Pn1 = a1 - (K0 * r01 + K1 * r11);
        const float Pn2 = a2 - (K0 * r02 + K1 * r12);
        const float Pn3 = a3 - (K0 * r03 + K1 * r13);

        // condition table
        const int  l  = lv[k], m = mv[k];
        const bool c1  = (l == 0) && (m == 0);
        const bool c3  = (l != 0) && (m == 0);
        const bool c4  = (l != 0) && (m != 0);
        const bool c3a = c3 && (l <= 5);

        // rP row r: c1 -> diag(1,1,10,10) row, c3a -> pP, c4 -> Pn, else 0
        const float dv = (r < 2) ? 1.0f : 10.0f;
        float4 e;
        e.x = c1 ? ((r == 0) ? dv : 0.0f) : (c3a ? a0 : (c4 ? Pn0 : 0.0f));
        e.y = c1 ? ((r == 1) ? dv : 0.0f) : (c3a ? a1 : (c4 ? Pn1 : 0.0f));
        e.z = c1 ? ((r == 2) ? dv : 0.0f) : (c3a ? a2 : (c4 ? Pn2 : 0.0f));
        e.w = c1 ? ((r == 3) ? dv : 0.0f) : (c3a ? a3 : (c4 ? Pn3 : 0.0f));
        if (act[k])
            reinterpret_cast<float4*>(rP_out)[(size_t)t[k] * 4 + r] = e;

        // rv (rows 0,1) and rvel (rows 2,3)
        float  sval;
        float* sp;
        if (r < 2) {
            const float oc = (r == 0) ? o2[k].x : o2[k].y;
            sval = c4 ? updr : (c3 ? pr : oc);
            sp   = rv_out + (size_t)t[k] * 2 + r;
        } else {
            sval = c4 ? updr : (c3a ? pr : 0.0f);
            sp   = rvel_out + (size_t)t[k] * 2 + (r - 2);
        }
        if (act[k]) *sp = sval;

        // rm: (c2|c4) == (m != 0) -> 1, else c3a -> l+1, else 0
        const float rmv = (m != 0) ? 1.0f : (c3a ? (float)(l + 1) : 0.0f);
        if (act[k] && r == 0) rm_out[t[k]] = rmv;
    }
}

extern "C" void kernel_launch(void* const* d_in, const int* in_sizes, int n_in,
                              void* d_out, int out_size, void* d_ws, size_t ws_size,
                              hipStream_t stream) {
    const float* value = (const float*)d_in[0];
    const float* vel   = (const float*)d_in[1];
    const float* P     = (const float*)d_in[2];
    const float* obs   = (const float*)d_in[3];
    const int*   lm    = (const int*)d_in[4];
    const int*   mask  = (const int*)d_in[5];

    const int Bn     = in_sizes[0] / (2 * NUM);   // value is (B, 2*NUM)
    const int total  = Bn * NUM;
    const int blocks = (total + TRACKS_PER_BLOCK - 1) / TRACKS_PER_BLOCK;

    kf_update_kernel<<<blocks, TPB, 0, stream>>>(
        value, vel, P, obs, lm, mask, (float*)d_out, Bn);
}

// Round 4
// 175.215 us; speedup vs baseline: 1.0015x; 1.0015x over previous
//
#include <hip/hip_runtime.h>

#define NUM 16
#define TPB 256
#define TILES 4
#define TRACKS_PER_TILE (TPB / 4)                   // 64 tracks per tile per block
#define TRACKS_PER_BLOCK (TRACKS_PER_TILE * TILES)  // 256 tracks per block

typedef float f32x4 __attribute__((ext_vector_type(4)));
typedef float f32x2 __attribute__((ext_vector_type(2)));

// Round-9: forced MLP via inline-asm loads + counted vmcnt waits.
// Rounds 7/8 proved hipcc re-serializes C++ loads to minimize VGPR pressure
// (VGPR 24 then 36 vs the 48+ needed for 24 loads in flight), so the MLP
// theory was never actually tested. asm volatile loads cannot be reordered
// or register-shrunk: all 24 global_load_* issue before any compute, and
// each tile's compute begins at s_waitcnt vmcnt(18-6k) (in-order retire ->
// first 6(k+1) loads complete). sched_barrier(0) after each wait per rule
// #18 (compiler otherwise hoists dependent VALU above the waitcnt asm).
// All stores buffered in registers and emitted after the last wait, so the
// vmcnt arithmetic sees loads only.
__global__ __launch_bounds__(TPB, 4) void kf_update_kernel(
    const float* __restrict__ value,   // (B, 32)
    const float* __restrict__ vel,     // (B, 32)
    const float* __restrict__ Pin,     // (B, 16, 4, 4)
    const float* __restrict__ obs,     // (B, 32)
    const int*   __restrict__ lm,      // (B, 16)
    const int*   __restrict__ mask,    // (B, 16)
    float* __restrict__ out,           // rv(B*32) | rm(B*16) | rvel(B*32) | rP(B*256)
    int Bn)
{
    const int tid = threadIdx.x;
    const int r   = tid & 3;    // row of the 4x4 this lane owns
    const int sub = tid >> 2;   // track slot within block (0..63)
    const int total = Bn * NUM;

    const int base = blockIdx.x * TRACKS_PER_BLOCK + sub;

    int   t[TILES];
    bool  act[TILES];
    f32x4 Pr[TILES];
    f32x2 v2[TILES], u2[TILES], o2[TILES];
    int   lv[TILES], mv[TILES];

    // ---- issue ALL 24 loads via volatile asm (order pinned, regs pinned) ----
    #pragma unroll
    for (int k = 0; k < TILES; ++k) {
        t[k]   = base + k * TRACKS_PER_TILE;
        act[k] = t[k] < total;
        const int tc = act[k] ? t[k] : 0;
        const float* pP = Pin   + ((size_t)tc * 4 + r) * 4;
        const float* pV = value + (size_t)tc * 2;
        const float* pU = vel   + (size_t)tc * 2;
        const float* pO = obs   + (size_t)tc * 2;
        const int*   pL = lm    + tc;
        const int*   pM = mask  + tc;
        asm volatile("global_load_dwordx4 %0, %1, off" : "=v"(Pr[k]) : "v"(pP));
        asm volatile("global_load_dwordx2 %0, %1, off" : "=v"(v2[k]) : "v"(pV));
        asm volatile("global_load_dwordx2 %0, %1, off" : "=v"(u2[k]) : "v"(pU));
        asm volatile("global_load_dwordx2 %0, %1, off" : "=v"(o2[k]) : "v"(pO));
        asm volatile("global_load_dword   %0, %1, off" : "=v"(lv[k]) : "v"(pL));
        asm volatile("global_load_dword   %0, %1, off" : "=v"(mv[k]) : "v"(pM));
    }
    // Nothing may move up into (or out of) the load-issue block.
    __builtin_amdgcn_sched_barrier(0);

    f32x4 e[TILES];     // rP row to store
    float sv[TILES];    // rv (r<2) or rvel (r>=2) component
    float rmv[TILES];   // rm (lane r==0 stores)

// Per-tile: counted wait (loads 0..6*(K+1)-1 complete), fence, pure-reg compute.
#define KF_TILE(K, VMSTR)                                                     \
    do {                                                                      \
        asm volatile("s_waitcnt vmcnt(" VMSTR ")" ::: "memory");              \
        __builtin_amdgcn_sched_barrier(0);                                    \
        const float pr = (r == 0) ? (v2[K].x + u2[K].x)                       \
                       : (r == 1) ? (v2[K].y + u2[K].y)                       \
                       : (r == 2) ? u2[K].x                                   \
                                  : u2[K].y;                                  \
        float q0 = Pr[K].x, q1 = Pr[K].y, q2 = Pr[K].z, q3 = Pr[K].w;         \
        const float x0 = __shfl_xor(q0, 2);                                   \
        const float x1 = __shfl_xor(q1, 2);                                   \
        const float x2 = __shfl_xor(q2, 2);                                   \
        const float x3 = __shfl_xor(q3, 2);                                   \
        if (r < 2) { q0 += x0; q1 += x1; q2 += x2; q3 += x3; }                \
        const float a0 = q0 + q2;                                             \
        const float a1 = q1 + q3;                                             \
        const float a2 = q2;                                                  \
        const float a3 = q3;                                                  \
        const float r00 = __shfl(a0, 0, 4), r01 = __shfl(a1, 0, 4);           \
        const float r02 = __shfl(a2, 0, 4), r03 = __shfl(a3, 0, 4);           \
        const float r10 = __shfl(a0, 1, 4), r11 = __shfl(a1, 1, 4);           \
        const float r12 = __shfl(a2, 1, 4), r13 = __shfl(a3, 1, 4);           \
        const float S00 = r00 + 1e-5f;                                        \
        const float S01 = r01;                                                \
        const float S10 = r10;                                                \
        const float S11 = r11 + 1e-5f;                                        \
        const float rdet = 1.0f / (S00 * S11 - S01 * S10);                    \
        const float K0 = (a0 * S11 - a1 * S10) * rdet;                        \
        const float K1 = (a1 * S00 - a0 * S01) * rdet;                        \
        const float p0 = __shfl(pr, 0, 4);                                    \
        const float p1 = __shfl(pr, 1, 4);                                    \
        const float y0 = o2[K].x - p0;                                        \
        const float y1 = o2[K].y - p1;                                        \
        const float updr = pr + K0 * y0 + K1 * y1;                            \
        const float Pn0 = a0 - (K0 * r00 + K1 * r10);                         \
        const float Pn1 = a1 - (K0 * r01 + K1 * r11);                         \
        const float Pn2 = a2 - (K0 * r02 + K1 * r12);                         \
        const float Pn3 = a3 - (K0 * r03 + K1 * r13);                         \
        const int  l  = lv[K], m = mv[K];                                     \
        const bool c1  = (l == 0) && (m == 0);                                \
        const bool c3  = (l != 0) && (m == 0);                                \
        const bool c4  = (l != 0) && (m != 0);                                \
        const bool c3a = c3 && (l <= 5);                                      \
        const float dv = (r < 2) ? 1.0f : 10.0f;                              \
        e[K].x = c1 ? ((r == 0) ? dv : 0.0f) : (c3a ? a0 : (c4 ? Pn0 : 0.0f));\
        e[K].y = c1 ? ((r == 1) ? dv : 0.0f) : (c3a ? a1 : (c4 ? Pn1 : 0.0f));\
        e[K].z = c1 ? ((r == 2) ? dv : 0.0f) : (c3a ? a2 : (c4 ? Pn2 : 0.0f));\
        e[K].w = c1 ? ((r == 3) ? dv : 0.0f) : (c3a ? a3 : (c4 ? Pn3 : 0.0f));\
        if (r < 2) {                                                          \
            const float oc = (r == 0) ? o2[K].x : o2[K].y;                    \
            sv[K] = c4 ? updr : (c3 ? pr : oc);                               \
        } else {                                                              \
            sv[K] = c4 ? updr : (c3a ? pr : 0.0f);                            \
        }                                                                     \
        rmv[K] = (m != 0) ? 1.0f : (c3a ? (float)(l + 1) : 0.0f);             \
    } while (0)

    KF_TILE(0, "18");
    KF_TILE(1, "12");
    KF_TILE(2, "6");
    KF_TILE(3, "0");

#undef KF_TILE

    // ---- drain: all stores after the last wait (coalesced, same as r-3) ----
    float* __restrict__ rv_out   = out;
    float* __restrict__ rm_out   = out + (size_t)Bn * 32;
    float* __restrict__ rvel_out = out + (size_t)Bn * 48;
    float* __restrict__ rP_out   = out + (size_t)Bn * 80;

    #pragma unroll
    for (int k = 0; k < TILES; ++k) {
        if (act[k]) {
            reinterpret_cast<f32x4*>(rP_out)[(size_t)t[k] * 4 + r] = e[k];
            float* sp = (r < 2) ? (rv_out   + (size_t)t[k] * 2 + r)
                                : (rvel_out + (size_t)t[k] * 2 + (r - 2));
            *sp = sv[k];
            if (r == 0) rm_out[t[k]] = rmv[k];
        }
    }
}

extern "C" void kernel_launch(void* const* d_in, const int* in_sizes, int n_in,
                              void* d_out, int out_size, void* d_ws, size_t ws_size,
                              hipStream_t stream) {
    const float* value = (const float*)d_in[0];
    const float* vel   = (const float*)d_in[1];
    const float* P     = (const float*)d_in[2];
    const float* obs   = (const float*)d_in[3];
    const int*   lm    = (const int*)d_in[4];
    const int*   mask  = (const int*)d_in[5];

    const int Bn     = in_sizes[0] / (2 * NUM);   // value is (B, 2*NUM)
    const int total  = Bn * NUM;
    const int blocks = (total + TRACKS_PER_BLOCK - 1) / TRACKS_PER_BLOCK;

    kf_update_kernel<<<blocks, TPB, 0, stream>>>(
        value, vel, P, obs, lm, mask, (float*)d_out, Bn);
}